// Round 12
// baseline (1627.860 us; speedup 1.0000x reference)
//
#include <hip/hip_runtime.h>

#define DD 64
#define ALPHA 0.6f
#define KHOPS 8
#define WP 72   // LDS row stride in bf16 elems (144 B = 9*16B: aligned, 2-way banks)

typedef __attribute__((ext_vector_type(8))) short bf16x8;
typedef __attribute__((ext_vector_type(4))) float f32x4;

static __device__ __forceinline__ unsigned short f2bf(float f) {
    unsigned int u = __float_as_uint(f);
    unsigned int r = (u + 0x7FFFu + ((u >> 16) & 1u)) >> 16;   // RTN-even
    return (unsigned short)r;
}
static __device__ __forceinline__ unsigned int pack2bf(float lo, float hi) {
    return (unsigned int)f2bf(lo) | ((unsigned int)f2bf(hi) << 16);
}

// zero cnt (n16 uint4s) + the grid-barrier counter
__global__ __launch_bounds__(256) void zero_kernel(uint4* __restrict__ p, int n16,
                                                   unsigned int* __restrict__ bar) {
    int i = blockIdx.x * blockDim.x + threadIdx.x;
    if (i < n16) p[i] = make_uint4(0u, 0u, 0u, 0u);
    if (i == 0) *bar = 0u;
}

// XCD-partitioned degree count (cnt lines stay in one XCD's L2)
#define FCHUNK 2048
__global__ __launch_bounds__(256) void deg_count_kernel(const int* __restrict__ dst,
                                                        int* __restrict__ cnt,
                                                        int e, int n) {
    int xcd = blockIdx.x & 7;
    int chunk = blockIdx.x >> 3;
    int lo = (int)(((long long)n * xcd) >> 3);
    int hi = (int)(((long long)n * (xcd + 1)) >> 3);
    int base = chunk * FCHUNK + threadIdx.x * 8;
    if (base >= e) return;
    int4 d0 = *(const int4*)(dst + base);
    int4 d1 = *(const int4*)(dst + base + 4);
    int dv[8] = {d0.x, d0.y, d0.z, d0.w, d1.x, d1.y, d1.z, d1.w};
    #pragma unroll
    for (int j = 0; j < 8; ++j) {
        if (base + j < e) {
            int d = dv[j];
            if (d >= lo && d < hi) atomicAdd(&cnt[d], 1);
        }
    }
}

// block partial sums of cnt (+ dinvr table fused)
__global__ __launch_bounds__(256) void scan1_kernel(const int* __restrict__ cnt,
                                                    int* __restrict__ partials,
                                                    float2* __restrict__ dinvr, int n) {
    int i = blockIdx.x * 256 + threadIdx.x;
    int v = (i < n) ? cnt[i] : 0;
    if (i < n) {
        float d = (float)(v + 1);
        dinvr[i] = make_float2(rsqrtf(d), sqrtf(d));
    }
    int sum = v;
    #pragma unroll
    for (int off = 1; off < 64; off <<= 1) sum += __shfl_down(sum, off, 64);
    __shared__ int ws[4];
    if ((threadIdx.x & 63) == 0) ws[threadIdx.x >> 6] = sum;
    __syncthreads();
    if (threadIdx.x == 0) partials[blockIdx.x] = ws[0] + ws[1] + ws[2] + ws[3];
}

// fused scan2+scan3: every block redundantly scans the <=256 partials in LDS,
// then does its local element scan. rowptr/cursor out.
__global__ __launch_bounds__(256) void scan23_kernel(const int* __restrict__ cnt,
                                                     const int* __restrict__ partials,
                                                     int nb,
                                                     int* __restrict__ rowptr,
                                                     int* __restrict__ cursor, int n) {
    __shared__ int sp[256];
    int t = threadIdx.x;
    int pv = (t < nb) ? partials[t] : 0;
    sp[t] = pv;
    __syncthreads();
    for (int off = 1; off < 256; off <<= 1) {
        int tmp = (t >= off) ? sp[t - off] : 0;
        __syncthreads();
        sp[t] += tmp;
        __syncthreads();
    }
    int blockpre = sp[blockIdx.x] - partials[blockIdx.x];  // exclusive prefix @ block

    int i = blockIdx.x * 256 + t;
    int v = (i < n) ? cnt[i] : 0;
    int lane = t & 63;
    int incl = v;
    #pragma unroll
    for (int off = 1; off < 64; off <<= 1) {
        int u = __shfl_up(incl, off, 64);
        if (lane >= off) incl += u;
    }
    __shared__ int wsum[4];
    if (lane == 63) wsum[t >> 6] = incl;
    __syncthreads();
    int woff = 0;
    for (int w = 0; w < (t >> 6); ++w) woff += wsum[w];
    int excl = incl - v + woff + blockpre;
    if (i < n) { rowptr[i] = excl; cursor[i] = excl; }
    if (i == n - 1) rowptr[n] = excl + v;
}

// XCD-partitioned CSR fill (L2-local esrc/cursor lines)
__global__ __launch_bounds__(256) void fill_kernel(const int* __restrict__ src,
                                                   const int* __restrict__ dst,
                                                   int* __restrict__ cursor,
                                                   int* __restrict__ esrc, int e, int n) {
    int xcd = blockIdx.x & 7;
    int chunk = blockIdx.x >> 3;
    int lo = (int)(((long long)n * xcd) >> 3);
    int hi = (int)(((long long)n * (xcd + 1)) >> 3);
    int base = chunk * FCHUNK + threadIdx.x * 8;
    if (base >= e) return;
    int4 s0 = *(const int4*)(src + base);
    int4 s1 = *(const int4*)(src + base + 4);
    int4 d0 = *(const int4*)(dst + base);
    int4 d1 = *(const int4*)(dst + base + 4);
    int sv[8] = {s0.x, s0.y, s0.z, s0.w, s1.x, s1.y, s1.z, s1.w};
    int dv[8] = {d0.x, d0.y, d0.z, d0.w, d1.x, d1.y, d1.z, d1.w};
    #pragma unroll
    for (int j = 0; j < 8; ++j) {
        if (base + j < e) {
            int d = dv[j];
            if (d >= lo && d < hi) {
                int pos = atomicAdd(&cursor[d], 1);
                esrc[pos] = sv[j];
            }
        }
    }
}

static __device__ __forceinline__ void add8(float* acc, uint4 v) {
    acc[0] += __uint_as_float(v.x << 16);
    acc[1] += __uint_as_float(v.x & 0xffff0000u);
    acc[2] += __uint_as_float(v.y << 16);
    acc[3] += __uint_as_float(v.y & 0xffff0000u);
    acc[4] += __uint_as_float(v.z << 16);
    acc[5] += __uint_as_float(v.z & 0xffff0000u);
    acc[6] += __uint_as_float(v.w << 16);
    acc[7] += __uint_as_float(v.w & 0xffff0000u);
}

// Persistent propagation kernel (cooperative launch: all blocks co-resident).
// Phase 0: y0 = bf16(dinv*x). Then 8 hops, separated by a sense-free monotonic
// grid barrier (1 atomicAdd per block + agent-scope fences for XCD visibility).
// Each y_k is written exactly once (in phase k) on 128B-aligned rows.
__global__ __launch_bounds__(1024) void prop_kernel(const int* __restrict__ rowptr,
                                                    const int* __restrict__ esrc,
                                                    const float2* __restrict__ dinvr,
                                                    const float* __restrict__ x,
                                                    unsigned short* __restrict__ ybase,
                                                    unsigned int* __restrict__ bar,
                                                    size_t ystride, int n) {
    int gw = (int)((blockIdx.x * blockDim.x + threadIdx.x) >> 6);
    int nw = (int)((gridDim.x * blockDim.x) >> 6);
    int lane = threadIdx.x & 63;
    unsigned int nblk = gridDim.x;

    // phase 0: y0 (coalesced: 1 float/lane)
    for (int node = gw; node < n; node += nw) {
        float di = dinvr[node].x;
        float xv = x[(size_t)node * 64 + lane];
        ybase[(size_t)node * 64 + lane] = f2bf(di * xv);
    }

    int g = lane >> 3;
    int s = lane & 7;

    for (int k = 1; k <= KHOPS; ++k) {
        // ---- grid barrier (generation k): release writes, arrive, spin, acquire
        __threadfence();
        __syncthreads();
        if (threadIdx.x == 0) {
            __hip_atomic_fetch_add(bar, 1u, __ATOMIC_RELEASE,
                                   __HIP_MEMORY_SCOPE_AGENT);
            unsigned int target = nblk * (unsigned int)k;
            while (__hip_atomic_load(bar, __ATOMIC_ACQUIRE,
                                     __HIP_MEMORY_SCOPE_AGENT) < target)
                __builtin_amdgcn_s_sleep(2);
        }
        __syncthreads();
        __threadfence();

        const unsigned short* yin = ybase + (size_t)(k - 1) * ystride;
        unsigned short* yout = ybase + (size_t)k * ystride;

        for (int node = gw; node < n; node += nw) {
            int e0 = rowptr[node];
            int e1 = rowptr[node + 1];

            float acc[8] = {0.f, 0.f, 0.f, 0.f, 0.f, 0.f, 0.f, 0.f};
            float d2 = 0.f;

            if (g == 0) {   // self term (weight 1 in y-space)
                float di = dinvr[node].x;
                d2 = di * di;
                uint4 v = *(const uint4*)(yin + (size_t)node * 64 + s * 8);
                add8(acc, v);
            }

            int deg = e1 - e0;
            int niter = (deg + 7) >> 3;
            int clampe = e1 - 1;
            for (int i = 0; i < niter; i += 4) {
                int eA = e0 + (i << 3) + g;
                int eB = eA + 8, eC = eA + 16, eD = eA + 24;
                bool vA = eA < e1, vB = eB < e1, vC = eC < e1, vD = eD < e1;
                int sA = esrc[vA ? eA : clampe];
                int sB = esrc[vB ? eB : clampe];
                int sC = esrc[vC ? eC : clampe];
                int sD = esrc[vD ? eD : clampe];
                uint4 va = *(const uint4*)(yin + (size_t)sA * 64 + s * 8);
                uint4 vb = *(const uint4*)(yin + (size_t)sB * 64 + s * 8);
                uint4 vc = *(const uint4*)(yin + (size_t)sC * 64 + s * 8);
                uint4 vd = *(const uint4*)(yin + (size_t)sD * 64 + s * 8);
                if (!vA) va = make_uint4(0u, 0u, 0u, 0u);
                if (!vB) vb = make_uint4(0u, 0u, 0u, 0u);
                if (!vC) vc = make_uint4(0u, 0u, 0u, 0u);
                if (!vD) vd = make_uint4(0u, 0u, 0u, 0u);
                add8(acc, va);
                add8(acc, vb);
                add8(acc, vc);
                add8(acc, vd);
            }

            #pragma unroll
            for (int off = 8; off < 64; off <<= 1) {
                #pragma unroll
                for (int j = 0; j < 8; ++j) acc[j] += __shfl_xor(acc[j], off, 64);
            }

            if (g == 0) {
                uint4 o;
                o.x = pack2bf(d2 * acc[0], d2 * acc[1]);
                o.y = pack2bf(d2 * acc[2], d2 * acc[3]);
                o.z = pack2bf(d2 * acc[4], d2 * acc[5]);
                o.w = pack2bf(d2 * acc[6], d2 * acc[7]);
                *(uint4*)(yout + (size_t)node * 64 + s * 8) = o;
            }
        }
    }
}

// MFMA fused MLP with on-the-fly h:
// h[r][c] = ALPHA*x[r][c] + coef*rdeg[r]*sum_{k=1..8} y_k[r][c]
// then out = relu(relu(h Wc^T+bc) W1^T+b1) W2^T+b2
__global__ __launch_bounds__(256) void mlp_mfma_kernel(const float* __restrict__ x,
                                                       const float2* __restrict__ dinvr,
                                                       const unsigned short* __restrict__ yall,
                                                       size_t ystride, float coef,
                                                       const float* __restrict__ wc,
                                                       const float* __restrict__ bc,
                                                       const float* __restrict__ w1,
                                                       const float* __restrict__ b1,
                                                       const float* __restrict__ w2,
                                                       const float* __restrict__ b2,
                                                       float* __restrict__ out, int n) {
    __shared__ unsigned short wlds[3][64][WP];
    __shared__ unsigned short xlds[64][WP];
    int t = threadIdx.x;

    const float* wm[3] = {wc, w1, w2};
    #pragma unroll
    for (int m = 0; m < 3; ++m) {
        const float4* w4 = (const float4*)wm[m];
        #pragma unroll
        for (int k = 0; k < 4; ++k) {
            int fid = t + k * 256;               // 0..1023 float4s
            int j = fid >> 4, c4 = fid & 15;
            float4 v = w4[fid];
            *(uint2*)&wlds[m][j][c4 * 4] =
                make_uint2(pack2bf(v.x, v.y), pack2bf(v.z, v.w));
        }
    }

    int r0 = blockIdx.x * 64;
    const float4* x4 = (const float4*)x;
    #pragma unroll
    for (int k = 0; k < 4; ++k) {
        int fid = t + k * 256;
        int r = fid >> 4, c4 = fid & 15;
        int gr = r0 + r;
        float h0 = 0.f, h1 = 0.f, h2 = 0.f, h3 = 0.f;
        if (gr < n) {
            float4 xv = x4[(size_t)gr * 16 + c4];
            float ys0 = 0.f, ys1 = 0.f, ys2 = 0.f, ys3 = 0.f;
            #pragma unroll
            for (int kk = 1; kk <= KHOPS; ++kk) {
                uint2 u = *(const uint2*)(yall + (size_t)kk * ystride +
                                          (size_t)gr * 64 + c4 * 4);
                ys0 += __uint_as_float(u.x << 16);
                ys1 += __uint_as_float(u.x & 0xffff0000u);
                ys2 += __uint_as_float(u.y << 16);
                ys3 += __uint_as_float(u.y & 0xffff0000u);
            }
            float cr = coef * dinvr[gr].y;   // coef * rdeg
            h0 = ALPHA * xv.x + cr * ys0;
            h1 = ALPHA * xv.y + cr * ys1;
            h2 = ALPHA * xv.z + cr * ys2;
            h3 = ALPHA * xv.w + cr * ys3;
        }
        *(uint2*)&xlds[r][c4 * 4] = make_uint2(pack2bf(h0, h1), pack2bf(h2, h3));
    }
    __syncthreads();

    int lane = t & 63;
    int wv = t >> 6;
    int rbase = wv * 16;
    int lr = lane & 15;
    int kg = lane >> 4;
    const float* bias[3] = {bc, b1, b2};

    #pragma unroll
    for (int m = 0; m < 3; ++m) {
        bf16x8 a0 = *(bf16x8*)&xlds[rbase + lr][kg * 8];
        bf16x8 a1 = *(bf16x8*)&xlds[rbase + lr][32 + kg * 8];
        #pragma unroll
        for (int ct = 0; ct < 4; ++ct) {
            bf16x8 bv0 = *(bf16x8*)&wlds[m][ct * 16 + lr][kg * 8];
            bf16x8 bv1 = *(bf16x8*)&wlds[m][ct * 16 + lr][32 + kg * 8];
            f32x4 acc = {0.f, 0.f, 0.f, 0.f};
            acc = __builtin_amdgcn_mfma_f32_16x16x32_bf16(a0, bv0, acc, 0, 0, 0);
            acc = __builtin_amdgcn_mfma_f32_16x16x32_bf16(a1, bv1, acc, 0, 0, 0);
            float bb = bias[m][ct * 16 + lr];
            if (m < 2) {
                #pragma unroll
                for (int rg = 0; rg < 4; ++rg) {
                    float v = fmaxf(acc[rg] + bb, 0.0f);
                    xlds[rbase + kg * 4 + rg][ct * 16 + lr] = f2bf(v);
                }
            } else {
                #pragma unroll
                for (int rg = 0; rg < 4; ++rg) {
                    int gr = r0 + rbase + kg * 4 + rg;
                    if (gr < n) out[(size_t)gr * 64 + ct * 16 + lr] = acc[rg] + bb;
                }
            }
        }
        // wave reads only its own 16 rows next layer: program order suffices
    }
}

extern "C" void kernel_launch(void* const* d_in, const int* in_sizes, int n_in,
                              void* d_out, int out_size, void* d_ws, size_t ws_size,
                              hipStream_t stream) {
    const float* x      = (const float*)d_in[0];
    const float* w_conv = (const float*)d_in[1];
    const float* b_conv = (const float*)d_in[2];
    const float* w1     = (const float*)d_in[3];
    const float* b1     = (const float*)d_in[4];
    const float* w2     = (const float*)d_in[5];
    const float* b2     = (const float*)d_in[6];
    const int*   ei     = (const int*)d_in[7];

    int n = in_sizes[0] / DD;       // 50000
    int e = in_sizes[7] / 2;        // 800000
    const int* src = ei;
    const int* dst = ei + e;

    // workspace layout (explicit byte offsets)
    char* wsb = (char*)d_ws;
    int*    cnt      = (int*)(wsb + 0);                       // 256 KB slot
    float2* dinvr    = (float2*)(wsb + 256 * 1024);           // 512 KB slot
    int*    rowptr   = (int*)(wsb + 768 * 1024);              // 256 KB slot
    int*    cursor   = (int*)(wsb + 1024 * 1024);             // 256 KB slot
    int*    partials = (int*)(wsb + 1280 * 1024);             // 4 KB used
    unsigned int* bar = (unsigned int*)(wsb + 1280 * 1024 + 4096);  // own line
    int*    esrc     = (int*)(wsb + 1344 * 1024);             // e*4 = 3.2 MB
    unsigned short* ybase = (unsigned short*)(wsb + 1344 * 1024 + (size_t)e * 4);
    size_t ystride = (size_t)n * DD;                          // elems per y_k (6.4 MB)
    // y_k = ybase + k*ystride, k = 0..KHOPS  (57.6 MB total)

    const int B = 256;
    int nb = (n + 255) / 256;
    int nchunks = (e + FCHUNK - 1) / FCHUNK;

    int n16 = (n + 3) / 4;
    zero_kernel<<<(n16 + B - 1) / B, B, 0, stream>>>((uint4*)cnt, n16, bar);
    deg_count_kernel<<<nchunks * 8, B, 0, stream>>>(dst, cnt, e, n);
    scan1_kernel<<<nb, B, 0, stream>>>(cnt, partials, dinvr, n);
    scan23_kernel<<<nb, B, 0, stream>>>(cnt, partials, nb, rowptr, cursor, n);
    fill_kernel<<<nchunks * 8, B, 0, stream>>>(src, dst, cursor, esrc, e, n);

    // persistent propagation: cooperative launch guarantees co-residency
    int cus = 0;
    if (hipDeviceGetAttribute(&cus, hipDeviceAttributeMultiprocessorCount, 0)
            != hipSuccess || cus < 1)
        cus = 256;
    int occ = 0;
    if (hipOccupancyMaxActiveBlocksPerMultiprocessor(&occ, prop_kernel, 1024, 0)
            != hipSuccess || occ < 1)
        occ = 1;
    int pgrid = occ * cus;
    int maxblk = (int)(((size_t)n * 64 + 1023) / 1024);   // no more blocks than work
    if (pgrid > maxblk) pgrid = maxblk;

    const int* rowptr_c = rowptr;
    const int* esrc_c = esrc;
    const float2* dinvr_c = dinvr;
    const float* x_c = x;
    int n_v = n;
    void* pargs[] = {(void*)&rowptr_c, (void*)&esrc_c, (void*)&dinvr_c,
                     (void*)&x_c, (void*)&ybase, (void*)&bar,
                     (void*)&ystride, (void*)&n_v};
    hipLaunchCooperativeKernel(prop_kernel, dim3(pgrid), dim3(1024), pargs, 0, stream);

    float coef = (1.0f - ALPHA) / (float)KHOPS;
    mlp_mfma_kernel<<<(n + 63) / 64, B, 0, stream>>>(
        x, dinvr, ybase, ystride, coef, w_conv, b_conv, w1, b1, w2, b2,
        (float*)d_out, n);
}

// Round 13
// 271.729 us; speedup vs baseline: 5.9907x; 5.9907x over previous
//
#include <hip/hip_runtime.h>

#define DD 64
#define ALPHA 0.6f
#define KHOPS 8
#define WP 72   // LDS row stride in bf16 elems (144 B = 9*16B: aligned, 2-way banks)

typedef __attribute__((ext_vector_type(8))) short bf16x8;
typedef __attribute__((ext_vector_type(4))) float f32x4;

static __device__ __forceinline__ unsigned short f2bf(float f) {
    unsigned int u = __float_as_uint(f);
    unsigned int r = (u + 0x7FFFu + ((u >> 16) & 1u)) >> 16;   // RTN-even
    return (unsigned short)r;
}
static __device__ __forceinline__ unsigned int pack2bf(float lo, float hi) {
    return (unsigned int)f2bf(lo) | ((unsigned int)f2bf(hi) << 16);
}

// zero n16 uint4s
__global__ __launch_bounds__(256) void zero_kernel(uint4* __restrict__ p, int n16) {
    int i = blockIdx.x * blockDim.x + threadIdx.x;
    if (i < n16) p[i] = make_uint4(0u, 0u, 0u, 0u);
}

// XCD-partitioned degree count (cnt lines stay in one XCD's L2)
#define FCHUNK 2048
__global__ __launch_bounds__(256) void deg_count_kernel(const int* __restrict__ dst,
                                                        int* __restrict__ cnt,
                                                        int e, int n) {
    int xcd = blockIdx.x & 7;
    int chunk = blockIdx.x >> 3;
    int lo = (int)(((long long)n * xcd) >> 3);
    int hi = (int)(((long long)n * (xcd + 1)) >> 3);
    int base = chunk * FCHUNK + threadIdx.x * 8;
    if (base >= e) return;
    int4 d0 = *(const int4*)(dst + base);
    int4 d1 = *(const int4*)(dst + base + 4);
    int dv[8] = {d0.x, d0.y, d0.z, d0.w, d1.x, d1.y, d1.z, d1.w};
    #pragma unroll
    for (int j = 0; j < 8; ++j) {
        if (base + j < e) {
            int d = dv[j];
            if (d >= lo && d < hi) atomicAdd(&cnt[d], 1);
        }
    }
}

// block partial sums of cnt (+ dinvr table fused)
__global__ __launch_bounds__(256) void scan1_kernel(const int* __restrict__ cnt,
                                                    int* __restrict__ partials,
                                                    float2* __restrict__ dinvr, int n) {
    int i = blockIdx.x * 256 + threadIdx.x;
    int v = (i < n) ? cnt[i] : 0;
    if (i < n) {
        float d = (float)(v + 1);
        dinvr[i] = make_float2(rsqrtf(d), sqrtf(d));
    }
    int sum = v;
    #pragma unroll
    for (int off = 1; off < 64; off <<= 1) sum += __shfl_down(sum, off, 64);
    __shared__ int ws[4];
    if ((threadIdx.x & 63) == 0) ws[threadIdx.x >> 6] = sum;
    __syncthreads();
    if (threadIdx.x == 0) partials[blockIdx.x] = ws[0] + ws[1] + ws[2] + ws[3];
}

// fused scan2+scan3: every block redundantly scans the <=256 partials in LDS,
// then does its local element scan. rowptr/cursor out.
__global__ __launch_bounds__(256) void scan23_kernel(const int* __restrict__ cnt,
                                                     const int* __restrict__ partials,
                                                     int nb,
                                                     int* __restrict__ rowptr,
                                                     int* __restrict__ cursor, int n) {
    __shared__ int sp[256];
    int t = threadIdx.x;
    int pv = (t < nb) ? partials[t] : 0;
    sp[t] = pv;
    __syncthreads();
    for (int off = 1; off < 256; off <<= 1) {
        int tmp = (t >= off) ? sp[t - off] : 0;
        __syncthreads();
        sp[t] += tmp;
        __syncthreads();
    }
    int blockpre = sp[blockIdx.x] - partials[blockIdx.x];  // exclusive prefix @ block

    int i = blockIdx.x * 256 + t;
    int v = (i < n) ? cnt[i] : 0;
    int lane = t & 63;
    int incl = v;
    #pragma unroll
    for (int off = 1; off < 64; off <<= 1) {
        int u = __shfl_up(incl, off, 64);
        if (lane >= off) incl += u;
    }
    __shared__ int wsum[4];
    if (lane == 63) wsum[t >> 6] = incl;
    __syncthreads();
    int woff = 0;
    for (int w = 0; w < (t >> 6); ++w) woff += wsum[w];
    int excl = incl - v + woff + blockpre;
    if (i < n) { rowptr[i] = excl; cursor[i] = excl; }
    if (i == n - 1) rowptr[n] = excl + v;
}

// XCD-partitioned CSR fill (L2-local esrc/cursor lines)
__global__ __launch_bounds__(256) void fill_kernel(const int* __restrict__ src,
                                                   const int* __restrict__ dst,
                                                   int* __restrict__ cursor,
                                                   int* __restrict__ esrc, int e, int n) {
    int xcd = blockIdx.x & 7;
    int chunk = blockIdx.x >> 3;
    int lo = (int)(((long long)n * xcd) >> 3);
    int hi = (int)(((long long)n * (xcd + 1)) >> 3);
    int base = chunk * FCHUNK + threadIdx.x * 8;
    if (base >= e) return;
    int4 s0 = *(const int4*)(src + base);
    int4 s1 = *(const int4*)(src + base + 4);
    int4 d0 = *(const int4*)(dst + base);
    int4 d1 = *(const int4*)(dst + base + 4);
    int sv[8] = {s0.x, s0.y, s0.z, s0.w, s1.x, s1.y, s1.z, s1.w};
    int dv[8] = {d0.x, d0.y, d0.z, d0.w, d1.x, d1.y, d1.z, d1.w};
    #pragma unroll
    for (int j = 0; j < 8; ++j) {
        if (base + j < e) {
            int d = dv[j];
            if (d >= lo && d < hi) {
                int pos = atomicAdd(&cursor[d], 1);
                esrc[pos] = sv[j];
            }
        }
    }
}

// y0 = bf16(dinv * x)   (h is never materialized: deferred to the MLP)
__global__ __launch_bounds__(256) void init_kernel(const float4* __restrict__ x,
                                                   const float2* __restrict__ dinvr,
                                                   ushort4* __restrict__ yb, int n4) {
    int i = blockIdx.x * blockDim.x + threadIdx.x;
    if (i >= n4) return;
    int row = i >> 4;
    float di = dinvr[row].x;
    float4 v = x[i];
    ushort4 b;
    b.x = f2bf(di * v.x); b.y = f2bf(di * v.y);
    b.z = f2bf(di * v.z); b.w = f2bf(di * v.w);
    yb[i] = b;
}

static __device__ __forceinline__ void add8(float* acc, uint4 v) {
    acc[0] += __uint_as_float(v.x << 16);
    acc[1] += __uint_as_float(v.x & 0xffff0000u);
    acc[2] += __uint_as_float(v.y << 16);
    acc[3] += __uint_as_float(v.y & 0xffff0000u);
    acc[4] += __uint_as_float(v.z << 16);
    acc[5] += __uint_as_float(v.z & 0xffff0000u);
    acc[6] += __uint_as_float(v.w << 16);
    acc[7] += __uint_as_float(v.w & 0xffff0000u);
}

// y-space hop: S = sum_e y[src] + y[node]; y' = dinv^2 * S.  No h work.
// One wave per node; 8 groups x 8 lanes; 4 masked octets in flight.
__global__ __launch_bounds__(256) void hop_kernel(const int* __restrict__ rowptr,
                                                  const int* __restrict__ esrc,
                                                  const float2* __restrict__ dinvr,
                                                  const unsigned short* __restrict__ yin,
                                                  unsigned short* __restrict__ yout,
                                                  int n) {
    int wid = (blockIdx.x * blockDim.x + threadIdx.x) >> 6;   // wave id = node
    if (wid >= n) return;
    int lane = threadIdx.x & 63;
    int g = lane >> 3;
    int s = lane & 7;
    int node = wid;

    int e0 = rowptr[node];
    int e1 = rowptr[node + 1];

    float acc[8] = {0.f, 0.f, 0.f, 0.f, 0.f, 0.f, 0.f, 0.f};
    float d2 = 0.f;

    if (g == 0) {   // self term (weight 1 in y-space)
        float di = dinvr[node].x;
        d2 = di * di;
        uint4 v = *(const uint4*)(yin + (size_t)node * 64 + s * 8);
        add8(acc, v);
    }

    int deg = e1 - e0;
    int niter = (deg + 7) >> 3;     // octet count
    int clampe = e1 - 1;
    for (int i = 0; i < niter; i += 4) {
        int eA = e0 + (i << 3) + g;
        int eB = eA + 8, eC = eA + 16, eD = eA + 24;
        bool vA = eA < e1, vB = eB < e1, vC = eC < e1, vD = eD < e1;
        int sA = esrc[vA ? eA : clampe];
        int sB = esrc[vB ? eB : clampe];
        int sC = esrc[vC ? eC : clampe];
        int sD = esrc[vD ? eD : clampe];
        uint4 va = *(const uint4*)(yin + (size_t)sA * 64 + s * 8);
        uint4 vb = *(const uint4*)(yin + (size_t)sB * 64 + s * 8);
        uint4 vc = *(const uint4*)(yin + (size_t)sC * 64 + s * 8);
        uint4 vd = *(const uint4*)(yin + (size_t)sD * 64 + s * 8);
        if (!vA) va = make_uint4(0u, 0u, 0u, 0u);
        if (!vB) vb = make_uint4(0u, 0u, 0u, 0u);
        if (!vC) vc = make_uint4(0u, 0u, 0u, 0u);
        if (!vD) vd = make_uint4(0u, 0u, 0u, 0u);
        add8(acc, va);
        add8(acc, vb);
        add8(acc, vc);
        add8(acc, vd);
    }

    #pragma unroll
    for (int off = 8; off < 64; off <<= 1) {
        #pragma unroll
        for (int j = 0; j < 8; ++j) acc[j] += __shfl_xor(acc[j], off, 64);
    }

    if (g == 0) {
        uint4 o;
        o.x = pack2bf(d2 * acc[0], d2 * acc[1]);
        o.y = pack2bf(d2 * acc[2], d2 * acc[3]);
        o.z = pack2bf(d2 * acc[4], d2 * acc[5]);
        o.w = pack2bf(d2 * acc[6], d2 * acc[7]);
        *(uint4*)(yout + (size_t)node * 64 + s * 8) = o;
    }
}

// MFMA fused MLP with on-the-fly h:
// h[r][c] = ALPHA*x[r][c] + coef*rdeg[r]*sum_{k=1..8} y_k[r][c]
// then out = relu(relu(h Wc^T+bc) W1^T+b1) W2^T+b2
__global__ __launch_bounds__(256) void mlp_mfma_kernel(const float* __restrict__ x,
                                                       const float2* __restrict__ dinvr,
                                                       const unsigned short* __restrict__ yall,
                                                       size_t ystride, float coef,
                                                       const float* __restrict__ wc,
                                                       const float* __restrict__ bc,
                                                       const float* __restrict__ w1,
                                                       const float* __restrict__ b1,
                                                       const float* __restrict__ w2,
                                                       const float* __restrict__ b2,
                                                       float* __restrict__ out, int n) {
    __shared__ unsigned short wlds[3][64][WP];
    __shared__ unsigned short xlds[64][WP];
    int t = threadIdx.x;

    const float* wm[3] = {wc, w1, w2};
    #pragma unroll
    for (int m = 0; m < 3; ++m) {
        const float4* w4 = (const float4*)wm[m];
        #pragma unroll
        for (int k = 0; k < 4; ++k) {
            int fid = t + k * 256;               // 0..1023 float4s
            int j = fid >> 4, c4 = fid & 15;
            float4 v = w4[fid];
            *(uint2*)&wlds[m][j][c4 * 4] =
                make_uint2(pack2bf(v.x, v.y), pack2bf(v.z, v.w));
        }
    }

    int r0 = blockIdx.x * 64;
    const float4* x4 = (const float4*)x;
    #pragma unroll
    for (int k = 0; k < 4; ++k) {
        int fid = t + k * 256;
        int r = fid >> 4, c4 = fid & 15;
        int gr = r0 + r;
        float h0 = 0.f, h1 = 0.f, h2 = 0.f, h3 = 0.f;
        if (gr < n) {
            float4 xv = x4[(size_t)gr * 16 + c4];
            float ys0 = 0.f, ys1 = 0.f, ys2 = 0.f, ys3 = 0.f;
            #pragma unroll
            for (int kk = 1; kk <= KHOPS; ++kk) {
                uint2 u = *(const uint2*)(yall + (size_t)kk * ystride +
                                          (size_t)gr * 64 + c4 * 4);
                ys0 += __uint_as_float(u.x << 16);
                ys1 += __uint_as_float(u.x & 0xffff0000u);
                ys2 += __uint_as_float(u.y << 16);
                ys3 += __uint_as_float(u.y & 0xffff0000u);
            }
            float cr = coef * dinvr[gr].y;   // coef * rdeg
            h0 = ALPHA * xv.x + cr * ys0;
            h1 = ALPHA * xv.y + cr * ys1;
            h2 = ALPHA * xv.z + cr * ys2;
            h3 = ALPHA * xv.w + cr * ys3;
        }
        *(uint2*)&xlds[r][c4 * 4] = make_uint2(pack2bf(h0, h1), pack2bf(h2, h3));
    }
    __syncthreads();

    int lane = t & 63;
    int wv = t >> 6;
    int rbase = wv * 16;
    int lr = lane & 15;
    int kg = lane >> 4;
    const float* bias[3] = {bc, b1, b2};

    #pragma unroll
    for (int m = 0; m < 3; ++m) {
        bf16x8 a0 = *(bf16x8*)&xlds[rbase + lr][kg * 8];
        bf16x8 a1 = *(bf16x8*)&xlds[rbase + lr][32 + kg * 8];
        #pragma unroll
        for (int ct = 0; ct < 4; ++ct) {
            bf16x8 bv0 = *(bf16x8*)&wlds[m][ct * 16 + lr][kg * 8];
            bf16x8 bv1 = *(bf16x8*)&wlds[m][ct * 16 + lr][32 + kg * 8];
            f32x4 acc = {0.f, 0.f, 0.f, 0.f};
            acc = __builtin_amdgcn_mfma_f32_16x16x32_bf16(a0, bv0, acc, 0, 0, 0);
            acc = __builtin_amdgcn_mfma_f32_16x16x32_bf16(a1, bv1, acc, 0, 0, 0);
            float bb = bias[m][ct * 16 + lr];
            if (m < 2) {
                #pragma unroll
                for (int rg = 0; rg < 4; ++rg) {
                    float v = fmaxf(acc[rg] + bb, 0.0f);
                    xlds[rbase + kg * 4 + rg][ct * 16 + lr] = f2bf(v);
                }
            } else {
                #pragma unroll
                for (int rg = 0; rg < 4; ++rg) {
                    int gr = r0 + rbase + kg * 4 + rg;
                    if (gr < n) out[(size_t)gr * 64 + ct * 16 + lr] = acc[rg] + bb;
                }
            }
        }
        // wave reads only its own 16 rows next layer: program order suffices
    }
}

extern "C" void kernel_launch(void* const* d_in, const int* in_sizes, int n_in,
                              void* d_out, int out_size, void* d_ws, size_t ws_size,
                              hipStream_t stream) {
    const float* x      = (const float*)d_in[0];
    const float* w_conv = (const float*)d_in[1];
    const float* b_conv = (const float*)d_in[2];
    const float* w1     = (const float*)d_in[3];
    const float* b1     = (const float*)d_in[4];
    const float* w2     = (const float*)d_in[5];
    const float* b2     = (const float*)d_in[6];
    const int*   ei     = (const int*)d_in[7];

    int n = in_sizes[0] / DD;       // 50000
    int e = in_sizes[7] / 2;        // 800000
    const int* src = ei;
    const int* dst = ei + e;

    // workspace layout (explicit byte offsets)
    char* wsb = (char*)d_ws;
    int*    cnt      = (int*)(wsb + 0);                       // 256 KB slot
    float2* dinvr    = (float2*)(wsb + 256 * 1024);           // 512 KB slot
    int*    rowptr   = (int*)(wsb + 768 * 1024);              // 256 KB slot
    int*    cursor   = (int*)(wsb + 1024 * 1024);             // 256 KB slot
    int*    partials = (int*)(wsb + 1280 * 1024);             // 4 KB used
    int*    esrc     = (int*)(wsb + 1344 * 1024);             // e*4 = 3.2 MB
    unsigned short* ybase = (unsigned short*)(wsb + 1344 * 1024 + (size_t)e * 4);
    size_t ystride = (size_t)n * DD;                          // elems per y_k (6.4 MB)
    // y_k = ybase + k*ystride, k = 0..KHOPS  (57.6 MB total)

    const int B = 256;
    int n4 = n * (DD / 4);
    int nb = (n + 255) / 256;
    int nchunks = (e + FCHUNK - 1) / FCHUNK;

    int n16 = (n + 3) / 4;
    zero_kernel<<<(n16 + B - 1) / B, B, 0, stream>>>((uint4*)cnt, n16);
    deg_count_kernel<<<nchunks * 8, B, 0, stream>>>(dst, cnt, e, n);
    scan1_kernel<<<nb, B, 0, stream>>>(cnt, partials, dinvr, n);
    scan23_kernel<<<nb, B, 0, stream>>>(cnt, partials, nb, rowptr, cursor, n);
    fill_kernel<<<nchunks * 8, B, 0, stream>>>(src, dst, cursor, esrc, e, n);

    init_kernel<<<(n4 + B - 1) / B, B, 0, stream>>>(
        (const float4*)x, dinvr, (ushort4*)ybase, n4);

    float coef = (1.0f - ALPHA) / (float)KHOPS;
    int hblocks = (int)(((size_t)n * 64 + B - 1) / B);

    for (int k = 1; k <= KHOPS; ++k) {
        hop_kernel<<<hblocks, B, 0, stream>>>(rowptr, esrc, dinvr,
                                              ybase + (size_t)(k - 1) * ystride,
                                              ybase + (size_t)k * ystride, n);
    }

    mlp_mfma_kernel<<<(n + 63) / 64, B, 0, stream>>>(
        x, dinvr, ybase, ystride, coef, w_conv, b_conv, w1, b1, w2, b2,
        (float*)d_out, n);
}